// Round 1
// baseline (117.327 us; speedup 1.0000x reference)
//
#include <hip/hip_runtime.h>
#include <hip/hip_bf16.h>

// ContrastiveLoss: N=8192, D=256, NUM_IDS=1000, MARGIN=0.3
// sim = X X^T (bf16 MFMA), fused mask+loss epilogue, upper-triangle only.

#define NROWS 8192
#define DDIM  256
#define MARGINF 0.3f

typedef __attribute__((ext_vector_type(8))) short short8x;   // 8 bf16 (4 VGPRs)
typedef __attribute__((ext_vector_type(4))) float f32x4;     // 4 fp32 acc

// ---------- round-to-nearest-even f32 -> bf16 bits ----------
__device__ __forceinline__ unsigned short f2bf(float f) {
    unsigned int u = __float_as_uint(f);
    unsigned int r = (u + 0x7fffu + ((u >> 16) & 1u)) >> 16;
    return (unsigned short)r;
}

// ---------- pass 1: fp32 -> bf16 convert (2M elems, 8/thread) ----------
__global__ void __launch_bounds__(256) convert_k(const float* __restrict__ x,
                                                 unsigned short* __restrict__ xb) {
    int i = blockIdx.x * 256 + threadIdx.x;          // 0 .. 262143
    const float4* p = reinterpret_cast<const float4*>(x) + (size_t)i * 2;
    float4 a = p[0];
    float4 b = p[1];
    short8x o;
    o[0] = (short)f2bf(a.x); o[1] = (short)f2bf(a.y);
    o[2] = (short)f2bf(a.z); o[3] = (short)f2bf(a.w);
    o[4] = (short)f2bf(b.x); o[5] = (short)f2bf(b.y);
    o[6] = (short)f2bf(b.z); o[7] = (short)f2bf(b.w);
    reinterpret_cast<short8x*>(xb)[i] = o;
}

// ---------- pass 2: fused GEMM + contrastive-loss epilogue ----------
// 128x128 tile per block, 4 waves (2x2), each wave 64x64 via 4x4 of 16x16x32 MFMA.
// BK=64: LDS tile [128][64] bf16 = 16KB each for A,B. XOR swizzle chunk^=(row&7)
// applied on BOTH the global_load_lds source address and the ds_read address.
__global__ void __launch_bounds__(256) gemm_loss_k(const unsigned short* __restrict__ xb,
                                                   const int* __restrict__ tg,
                                                   double* __restrict__ partials) {
    const int bj = blockIdx.x;   // col tile
    const int bi = blockIdx.y;   // row tile
    const int bid = bi * 64 + bj;

    if (bj < bi) {               // lower triangle: contribute 0, exit
        if (threadIdx.x == 0) partials[bid] = 0.0;
        return;
    }

    __shared__ unsigned short lA[128 * 64];   // 16 KB
    __shared__ unsigned short lB[128 * 64];   // 16 KB
    __shared__ int lti[128];
    __shared__ int ltj[128];
    __shared__ float redbuf[4];

    const int tid  = threadIdx.x;
    const int lane = tid & 63;
    const int wid  = tid >> 6;       // 0..3
    const int wr   = wid >> 1;       // wave row (0..1)
    const int wc   = wid & 1;        // wave col (0..1)

    if (tid < 128)       lti[tid]        = tg[bi * 128 + tid];
    else                 ltj[tid - 128]  = tg[bj * 128 + (tid - 128)];

    // ---- staging source addressing (pre-swizzled global source, linear LDS dest) ----
    // issue = 1KB = 8 rows of 128B. lane -> row (lane>>3), chunk (lane&7).
    // data for (row r, chunk c) is stored at LDS chunk c (linear), sourced from
    // global chunk c ^ (r&7)  (involution; ds_read applies the same XOR).
    const int lrow   = lane >> 3;                        // 0..7 row within issue
    const int schunk = ((lane & 7) ^ lrow) << 4;         // swizzled source byte offset

    const char* aBase = (const char*)(xb + (size_t)bi * 128 * 256);
    const char* bBase = (const char*)(xb + (size_t)bj * 128 * 256);

    // ---- ds_read fragment addressing ----
    // A frag (m,kk): row R = wr*64 + m*16 + (lane&15), k-chunk = kk*4 + (lane>>4)
    // byte = R*128 + ((chunk ^ (R&7))<<4);  R&7 == lane&7 here.
    const int g   = lane >> 4;        // 0..3
    const int x7  = lane & 7;
    const int rA  = wr * 64 + (lane & 15);
    const int rB  = wc * 64 + (lane & 15);
    // ushort index offsets
    int aoff[2], arow[4], brow[4];
#pragma unroll
    for (int kk = 0; kk < 2; ++kk) aoff[kk] = (((kk * 4 + g) ^ x7) << 3);
#pragma unroll
    for (int m = 0; m < 4; ++m) { arow[m] = (rA + m * 16) * 64; brow[m] = (rB + m * 16) * 64; }

    f32x4 acc[4][4] = {};

#pragma unroll
    for (int ks = 0; ks < 4; ++ks) {
        const int k0b = ks * 128;     // byte offset of this K-slab within a row (64 bf16)

        // ---- stage A and B tiles: 4 issues of 1KB per wave each ----
#pragma unroll
        for (int t = 0; t < 4; ++t) {
            const int issue = wid * 4 + t;              // 0..15
            const int r = issue * 8 + lrow;             // tile row 0..127
            const char* sa = aBase + (size_t)r * 512 + k0b + schunk;
            const char* sb = bBase + (size_t)r * 512 + k0b + schunk;
            __builtin_amdgcn_global_load_lds(
                (const __attribute__((address_space(1))) unsigned int*)sa,
                (__attribute__((address_space(3))) unsigned int*)&lA[issue * 512],
                16, 0, 0);
            __builtin_amdgcn_global_load_lds(
                (const __attribute__((address_space(1))) unsigned int*)sb,
                (__attribute__((address_space(3))) unsigned int*)&lB[issue * 512],
                16, 0, 0);
        }
        __syncthreads();   // drains vmcnt (compiler emits waitcnt before barrier)

        // ---- compute: 2 k-sub-steps of 16x16x32 ----
#pragma unroll
        for (int kk = 0; kk < 2; ++kk) {
            short8x af[4], bf[4];
#pragma unroll
            for (int m = 0; m < 4; ++m)
                af[m] = *(const short8x*)&lA[arow[m] + aoff[kk]];
#pragma unroll
            for (int n = 0; n < 4; ++n)
                bf[n] = *(const short8x*)&lB[brow[n] + aoff[kk]];
#pragma unroll
            for (int m = 0; m < 4; ++m)
#pragma unroll
                for (int n = 0; n < 4; ++n)
                    acc[m][n] = __builtin_amdgcn_mfma_f32_16x16x32_bf16(
                        af[m], bf[n], acc[m][n], 0, 0, 0);
        }
        __syncthreads();
    }

    // ---- epilogue: masks + loss, weighted for symmetry ----
    // C/D layout (m89): col = lane&15, row = (lane>>4)*4 + reg
    const bool diag = (bi == bj);
    const int colbase = wc * 64 + (lane & 15);
    float lsum = 0.f;
#pragma unroll
    for (int m = 0; m < 4; ++m) {
#pragma unroll
        for (int r = 0; r < 4; ++r) {
            const int rl = wr * 64 + m * 16 + (g << 2) + r;
            const int ti = lti[rl];
#pragma unroll
            for (int n = 0; n < 4; ++n) {
                const int cl = colbase + n * 16;
                const int tj = ltj[cl];
                const float s = acc[m][n][r];
                float contrib = (ti == tj) ? (s < 1.0f ? 1.0f - s : 0.0f)
                                           : (s > MARGINF ? s : 0.0f);
                float w = diag ? (cl > rl ? 2.0f : (cl == rl ? 1.0f : 0.0f)) : 2.0f;
                lsum += w * contrib;
            }
        }
    }

    // wave reduce then cross-wave
#pragma unroll
    for (int mask = 1; mask < 64; mask <<= 1) lsum += __shfl_xor(lsum, mask, 64);
    if (lane == 0) redbuf[wid] = lsum;
    __syncthreads();
    if (tid == 0)
        partials[bid] = (double)(redbuf[0] + redbuf[1] + redbuf[2] + redbuf[3]);
}

// ---------- pass 3: sum partials, divide by N ----------
__global__ void __launch_bounds__(256) finalize_k(const double* __restrict__ partials,
                                                  float* __restrict__ out) {
    double s = 0.0;
    for (int i = threadIdx.x; i < 4096; i += 256) s += partials[i];
#pragma unroll
    for (int mask = 1; mask < 64; mask <<= 1) s += __shfl_xor(s, mask, 64);
    __shared__ double red[4];
    const int wid = threadIdx.x >> 6;
    if ((threadIdx.x & 63) == 0) red[wid] = s;
    __syncthreads();
    if (threadIdx.x == 0)
        out[0] = (float)((red[0] + red[1] + red[2] + red[3]) / 8192.0);
}

extern "C" void kernel_launch(void* const* d_in, const int* in_sizes, int n_in,
                              void* d_out, int out_size, void* d_ws, size_t ws_size,
                              hipStream_t stream) {
    (void)in_sizes; (void)n_in; (void)out_size; (void)ws_size;
    const float* x  = (const float*)d_in[0];
    const int*   tg = (const int*)d_in[1];
    float* out = (float*)d_out;

    double* partials      = (double*)d_ws;                        // 4096 * 8B = 32KB
    unsigned short* xb    = (unsigned short*)((char*)d_ws + 32768); // 4MB bf16 X

    convert_k<<<1024, 256, 0, stream>>>(x, xb);
    gemm_loss_k<<<dim3(64, 64), 256, 0, stream>>>(xb, tg, partials);
    finalize_k<<<1, 256, 0, stream>>>(partials, out);
}

// Round 2
// 95.153 us; speedup vs baseline: 1.2330x; 1.2330x over previous
//
#include <hip/hip_runtime.h>
#include <hip/hip_bf16.h>

// ContrastiveLoss: N=8192, D=256, NUM_IDS=1000, MARGIN=0.3
// sim = X X^T (bf16 MFMA), fused mask+loss epilogue, upper-triangle only.
// R2: double-buffered LDS prefetch (T3-min 2-phase), 1D upper-tri grid,
//     slimmed epilogue.

#define NROWS 8192
#define DDIM  256
#define MARGINF 0.3f

typedef __attribute__((ext_vector_type(8))) short short8x;   // 8 bf16 (4 VGPRs)
typedef __attribute__((ext_vector_type(4))) float f32x4;     // 4 fp32 acc

// ---------- round-to-nearest-even f32 -> bf16 bits ----------
__device__ __forceinline__ unsigned short f2bf(float f) {
    unsigned int u = __float_as_uint(f);
    unsigned int r = (u + 0x7fffu + ((u >> 16) & 1u)) >> 16;
    return (unsigned short)r;
}

// ---------- pass 1: fp32 -> bf16 convert (2M elems, 8/thread) ----------
__global__ void __launch_bounds__(256) convert_k(const float* __restrict__ x,
                                                 unsigned short* __restrict__ xb) {
    int i = blockIdx.x * 256 + threadIdx.x;          // 0 .. 262143
    const float4* p = reinterpret_cast<const float4*>(x) + (size_t)i * 2;
    float4 a = p[0];
    float4 b = p[1];
    short8x o;
    o[0] = (short)f2bf(a.x); o[1] = (short)f2bf(a.y);
    o[2] = (short)f2bf(a.z); o[3] = (short)f2bf(a.w);
    o[4] = (short)f2bf(b.x); o[5] = (short)f2bf(b.y);
    o[6] = (short)f2bf(b.z); o[7] = (short)f2bf(b.w);
    reinterpret_cast<short8x*>(xb)[i] = o;
}

// ---------- pass 2: fused GEMM + contrastive-loss epilogue ----------
// 128x128 tile per block, 4 waves (2x2), each wave 64x64 via 4x4 of 16x16x32 MFMA.
// BK=64 double-buffered: LDS 2 x ([128][64] A + [128][64] B) = 64KB.
// XOR swizzle chunk^=(row&7) applied on BOTH the global_load_lds source address
// and the ds_read address (rule #21: linear LDS dest, pre-swizzled source).
__global__ void __launch_bounds__(256) gemm_loss_k(const unsigned short* __restrict__ xb,
                                                   const int* __restrict__ tg,
                                                   double* __restrict__ partials) {
    // ---- 1D upper-triangle decode: p -> (bi, bj), bi <= bj < 64 ----
    const int p = blockIdx.x;
    int bi = (int)(64.5f - sqrtf(64.5f * 64.5f - 2.0f * (float)p));
    if (bi < 0) bi = 0;
    if (bi > 63) bi = 63;
    while (bi > 0 && (bi * (129 - bi)) / 2 > p) --bi;
    while (((bi + 1) * (128 - bi)) / 2 <= p) ++bi;
    const int bj = bi + (p - (bi * (129 - bi)) / 2);

    __shared__ unsigned short lA[2][128 * 64];   // 2 x 16 KB
    __shared__ unsigned short lB[2][128 * 64];   // 2 x 16 KB
    __shared__ int lti[128];
    __shared__ int ltj[128];
    __shared__ float redbuf[4];

    const int tid  = threadIdx.x;
    const int lane = tid & 63;
    const int wid  = tid >> 6;       // 0..3
    const int wr   = wid >> 1;       // wave row (0..1)
    const int wc   = wid & 1;        // wave col (0..1)

    if (tid < 128)       lti[tid]        = tg[bi * 128 + tid];
    else                 ltj[tid - 128]  = tg[bj * 128 + (tid - 128)];

    // ---- staging addressing (pre-swizzled global source, linear LDS dest) ----
    // issue = 1KB = 8 rows of 128B. lane -> row (lane>>3), chunk (lane&7).
    // LDS[r][c] holds global[r][c ^ (r&7)] (involution; ds_read applies same XOR).
    const int lrow   = lane >> 3;                        // row within issue
    const int schunk = ((lane & 7) ^ lrow) << 4;         // swizzled source byte offset

    const char* aBase = (const char*)(xb + (size_t)bi * 128 * 256);
    const char* bBase = (const char*)(xb + (size_t)bj * 128 * 256);

    // ---- ds_read fragment addressing ----
    const int g   = lane >> 4;        // 0..3
    const int x7  = lane & 7;
    const int rA  = wr * 64 + (lane & 15);
    const int rB  = wc * 64 + (lane & 15);
    int aoff[2], arow[4], brow[4];
#pragma unroll
    for (int kk = 0; kk < 2; ++kk) aoff[kk] = (((kk * 4 + g) ^ x7) << 3);
#pragma unroll
    for (int m = 0; m < 4; ++m) { arow[m] = (rA + m * 16) * 64; brow[m] = (rB + m * 16) * 64; }

    f32x4 acc[4][4] = {};

    // stage one BK=64 slab (A+B) into buffer `buf`
    auto STAGE = [&](int buf, int ks) {
        const int k0b = ks * 128;     // byte offset of K-slab within a 512B row
#pragma unroll
        for (int t = 0; t < 4; ++t) {
            const int issue = wid * 4 + t;              // 0..15 (wave-uniform)
            const int r = issue * 8 + lrow;             // tile row 0..127
            const char* sa = aBase + (size_t)r * 512 + k0b + schunk;
            const char* sb = bBase + (size_t)r * 512 + k0b + schunk;
            __builtin_amdgcn_global_load_lds(
                (const __attribute__((address_space(1))) unsigned int*)sa,
                (__attribute__((address_space(3))) unsigned int*)&lA[buf][issue * 512],
                16, 0, 0);
            __builtin_amdgcn_global_load_lds(
                (const __attribute__((address_space(1))) unsigned int*)sb,
                (__attribute__((address_space(3))) unsigned int*)&lB[buf][issue * 512],
                16, 0, 0);
        }
    };

    STAGE(0, 0);
    __syncthreads();                 // drain vmcnt: buf0 ready

    int buf = 0;
#pragma unroll
    for (int ks = 0; ks < 4; ++ks) {
        if (ks < 3) STAGE(buf ^ 1, ks + 1);   // prefetch next slab (overlaps compute)

        const unsigned short* la = lA[buf];
        const unsigned short* lb = lB[buf];
#pragma unroll
        for (int kk = 0; kk < 2; ++kk) {
            short8x af[4], bf[4];
#pragma unroll
            for (int m = 0; m < 4; ++m)
                af[m] = *(const short8x*)&la[arow[m] + aoff[kk]];
#pragma unroll
            for (int n = 0; n < 4; ++n)
                bf[n] = *(const short8x*)&lb[brow[n] + aoff[kk]];
#pragma unroll
            for (int m = 0; m < 4; ++m)
#pragma unroll
                for (int n = 0; n < 4; ++n)
                    acc[m][n] = __builtin_amdgcn_mfma_f32_16x16x32_bf16(
                        af[m], bf[n], acc[m][n], 0, 0, 0);
        }

        if (ks < 3) { __syncthreads(); buf ^= 1; }  // drain prefetch, swap
    }

    // ---- epilogue: masks + loss ----
    // C/D layout (m89): col = lane&15, row = (lane>>4)*4 + reg
    const int colbase = wc * 64 + (lane & 15);
    int tjv[4];
#pragma unroll
    for (int n = 0; n < 4; ++n) tjv[n] = ltj[colbase + n * 16];

    float lsum = 0.f;
    if (bi != bj) {
        // off-diagonal tile: every element counts twice (symmetry)
#pragma unroll
        for (int m = 0; m < 4; ++m) {
#pragma unroll
            for (int r = 0; r < 4; ++r) {
                const int ti = lti[wr * 64 + m * 16 + (g << 2) + r];
#pragma unroll
                for (int n = 0; n < 4; ++n) {
                    const float s = acc[m][n][r];
                    const float posv = fmaxf(1.0f - s, 0.0f);
                    const float negv = (s > MARGINF) ? s : 0.0f;
                    lsum += (ti == tjv[n]) ? posv : negv;
                }
            }
        }
        lsum *= 2.0f;
    } else {
        // diagonal tile: strict-upper x2, diagonal x1, lower x0
#pragma unroll
        for (int m = 0; m < 4; ++m) {
#pragma unroll
            for (int r = 0; r < 4; ++r) {
                const int rl = wr * 64 + m * 16 + (g << 2) + r;
                const int ti = lti[rl];
#pragma unroll
                for (int n = 0; n < 4; ++n) {
                    const int cl = colbase + n * 16;
                    const float s = acc[m][n][r];
                    const float posv = fmaxf(1.0f - s, 0.0f);
                    const float negv = (s > MARGINF) ? s : 0.0f;
                    const float c = (ti == tjv[n]) ? posv : negv;
                    const float w = (cl > rl) ? 2.0f : ((cl == rl) ? 1.0f : 0.0f);
                    lsum += w * c;
                }
            }
        }
    }

    // wave reduce then cross-wave
#pragma unroll
    for (int mask = 1; mask < 64; mask <<= 1) lsum += __shfl_xor(lsum, mask, 64);
    if (lane == 0) redbuf[wid] = lsum;
    __syncthreads();
    if (tid == 0)
        partials[p] = (double)(redbuf[0] + redbuf[1] + redbuf[2] + redbuf[3]);
}

// ---------- pass 3: sum partials, divide by N ----------
__global__ void __launch_bounds__(256) finalize_k(const double* __restrict__ partials,
                                                  float* __restrict__ out) {
    double s = 0.0;
    for (int i = threadIdx.x; i < 2080; i += 256) s += partials[i];
#pragma unroll
    for (int mask = 1; mask < 64; mask <<= 1) s += __shfl_xor(s, mask, 64);
    __shared__ double red[4];
    const int wid = threadIdx.x >> 6;
    if ((threadIdx.x & 63) == 0) red[wid] = s;
    __syncthreads();
    if (threadIdx.x == 0)
        out[0] = (float)((red[0] + red[1] + red[2] + red[3]) / 8192.0);
}

extern "C" void kernel_launch(void* const* d_in, const int* in_sizes, int n_in,
                              void* d_out, int out_size, void* d_ws, size_t ws_size,
                              hipStream_t stream) {
    (void)in_sizes; (void)n_in; (void)out_size; (void)ws_size;
    const float* x  = (const float*)d_in[0];
    const int*   tg = (const int*)d_in[1];
    float* out = (float*)d_out;

    double* partials   = (double*)d_ws;                          // 2080 * 8B
    unsigned short* xb = (unsigned short*)((char*)d_ws + 32768); // 4MB bf16 X

    convert_k<<<1024, 256, 0, stream>>>(x, xb);
    gemm_loss_k<<<2080, 256, 0, stream>>>(xb, tg, partials);
    finalize_k<<<1, 256, 0, stream>>>(partials, out);
}